// Round 13
// baseline (360.391 us; speedup 1.0000x reference)
//
#include <hip/hip_runtime.h>
#include <stdint.h>

typedef __bf16 bf16x8 __attribute__((ext_vector_type(8)));
typedef float  f32x4  __attribute__((ext_vector_type(4)));

#define MFMA16(a, b, c) __builtin_amdgcn_mfma_f32_16x16x32_bf16((a), (b), (c), 0, 0, 0)

static constexpr int   kBz = 64, kNn = 577, kEe = 768, kHh = 8, kDd = 96;
static constexpr int   kM  = kBz * kNn;  // 36928 tokens
static constexpr float kScale = 0.10206207261596575f;  // 96^-0.5

__device__ __forceinline__ unsigned short f2bf(float f) {
  unsigned u = __float_as_uint(f);
  u += 0x7fffu + ((u >> 16) & 1u);  // RNE
  return (unsigned short)(u >> 16);
}
__device__ __forceinline__ float bf2f(unsigned short s) {
  return __uint_as_float(((unsigned)s) << 16);
}

__device__ __forceinline__ void gload16(const void* g, void* l) {
  __builtin_amdgcn_global_load_lds(
      (const __attribute__((address_space(1))) void*)(void*)g,
      (__attribute__((address_space(3))) void*)l, 16, 0, 0);
}

// ------ kernel 1: fused prep -- cast x to bf16 (blocks 0..27695) and build
// W^T bf16 [3*768 n][768 k] (blocks 27696..34607). ------
__global__ __launch_bounds__(256) void k_prep(const float* __restrict__ x,
                                              const float* __restrict__ Wq,
                                              const float* __restrict__ Wk,
                                              const float* __restrict__ Wv,
                                              unsigned short* __restrict__ xh,
                                              unsigned short* __restrict__ wcat) {
  const int b = blockIdx.x;
  if (b < 27696) {
    const int i = b * 256 + threadIdx.x;  // exact: 27696*256 == kM*kEe/4
    const float4 v = reinterpret_cast<const float4*>(x)[i];
    ushort4 h;
    h.x = f2bf(v.x); h.y = f2bf(v.y); h.z = f2bf(v.z); h.w = f2bf(v.w);
    reinterpret_cast<ushort4*>(xh)[i] = h;
  } else {
    const int o = (b - 27696) * 256 + threadIdx.x;  // exact: 6912*256 == 3*768*768
    const int gn = o / 768, k = o - gn * 768;
    const int mat = gn / 768, n = gn - mat * 768;
    const float* W = (mat == 0) ? Wq : ((mat == 1) ? Wk : Wv);
    wcat[o] = f2bf(W[k * 768 + n]);  // W is [k][n] row-major
  }
}

// ------- kernel 2: QKV projection GEMM, 128x128 tile, 4 waves, 8-phase -------
// A = xh (M=36928, K=768), B = wcat rows (N=2304). Single-bf16 outputs.
// 4 waves (2M x 2N), per-wave 64x64 output. LDS 64 KiB -> 2 BLOCKS/CU.
// SLOT MAP (R12 bug fix): read-half h is INTERLEAVED (rows {w*64+h*32..} ->
// slots {0-3,8-11} for h=0), so stage slots use (p>>2)*8+(p&3), NOT h*8+2w+j.
// Stage-half == read-half is what makes the 8-phase ledger sound.
#define MIDSYNC do { __builtin_amdgcn_s_barrier(); \
  asm volatile("s_waitcnt lgkmcnt(0)" ::: "memory"); \
  __builtin_amdgcn_sched_barrier(0); \
  __builtin_amdgcn_s_setprio(1); } while (0)
#define ENDPH do { __builtin_amdgcn_s_setprio(0); \
  __builtin_amdgcn_s_barrier(); \
  __builtin_amdgcn_sched_barrier(0); } while (0)
#define ENDPH_VM6 do { __builtin_amdgcn_s_setprio(0); \
  asm volatile("s_waitcnt vmcnt(6)" ::: "memory"); \
  __builtin_amdgcn_s_barrier(); \
  __builtin_amdgcn_sched_barrier(0); } while (0)
#define ENDPH_VM0 do { __builtin_amdgcn_s_setprio(0); \
  asm volatile("s_waitcnt vmcnt(0)" ::: "memory"); \
  __builtin_amdgcn_s_barrier(); \
  __builtin_amdgcn_sched_barrier(0); } while (0)

__global__ __launch_bounds__(256, 2) void k_proj(
    const unsigned short* __restrict__ xh, const unsigned short* __restrict__ wcat,
    const float* __restrict__ bq, const float* __restrict__ bk, const float* __restrict__ bv,
    unsigned short* __restrict__ Q, unsigned short* __restrict__ K,
    unsigned short* __restrict__ Vt) {
  extern __shared__ char smem[];  // 65536 B: A S0@0 S1@16384, B S0@32768 S1@49152
  const int tid = threadIdx.x, w = tid >> 6, l = tid & 63;
  const int wm = w >> 1, wn = w & 1;

  // bijective XCD swizzle: nwg=5202 = 8*650+2 -> q=650, r=2
  int bid = blockIdx.x;
  {
    const int xcd = bid & 7, i = bid >> 3;
    bid = ((xcd < 2) ? xcd * 651 : 2 * 651 + (xcd - 2) * 650) + i;
  }
  const int ntile = bid % 18, mtile = bid / 18;

  const int lrow8 = l >> 3;
  const int lc_sw = (l & 7) ^ lrow8;

  // stage slot ids matching interleaved read halves:
  // half 0 = slots {0,1,2,3, 8,9,10,11}; half 1 = +4.
  const int p0 = 2 * w, p1 = 2 * w + 1;
  int gAq[2][2], gBq[2][2];
  gAq[0][0] = (p0 >> 2) * 8 + (p0 & 3);
  gAq[0][1] = (p1 >> 2) * 8 + (p1 & 3);
  gAq[1][0] = gAq[0][0] + 4;
  gAq[1][1] = gAq[0][1] + 4;
  gBq[0][0] = gAq[0][0];
  gBq[0][1] = gAq[0][1];
  gBq[1][0] = gAq[1][0];
  gBq[1][1] = gAq[1][1];

  // hoisted global byte-voffsets
  unsigned voffA[2][2], voffB[2][2];
#pragma unroll
  for (int h = 0; h < 2; ++h)
#pragma unroll
    for (int j = 0; j < 2; ++j) {
      int m = mtile * 128 + 8 * gAq[h][j] + lrow8;
      if (m > kM - 1) m = kM - 1;
      voffA[h][j] = (unsigned)(m * 1536 + lc_sw * 16);
      const int bn = ntile * 128 + 8 * gBq[h][j] + lrow8;
      voffB[h][j] = (unsigned)(bn * 1536 + lc_sw * 16);
    }

  // hoisted LDS read base pointers [half][ks]
  const char* rdA[2][2];
  const char* rdB[2][2];
#pragma unroll
  for (int ks = 0; ks < 2; ++ks) {
    const int cks = (((ks * 4) + (l >> 4)) ^ (l & 7)) * 16;
#pragma unroll
    for (int h = 0; h < 2; ++h) {
      rdA[h][ks] = smem + (wm * 64 + h * 32 + (l & 15)) * 128 + cks;
      rdB[h][ks] = smem + 32768 + (wn * 64 + h * 32 + (l & 15)) * 128 + cks;
    }
  }

  const char* xbase = (const char*)xh;
  const char* wbase = (const char*)wcat;

  f32x4 acc[4][4];
  const f32x4 fz = {0.f, 0.f, 0.f, 0.f};
#pragma unroll
  for (int i = 0; i < 4; ++i)
#pragma unroll
    for (int j = 0; j < 4; ++j) acc[i][j] = fz;

  bf16x8 af[2][2], bfA[2][2], bfB[2][2];

  auto stA = [&](int Sb, int mh, unsigned koff) {
    gload16(xbase + koff + voffA[mh][0], smem + Sb + gAq[mh][0] * 1024);
    gload16(xbase + koff + voffA[mh][1], smem + Sb + gAq[mh][1] * 1024);
  };
  auto stB = [&](int Sb, int nh, unsigned koff) {
    gload16(wbase + koff + voffB[nh][0], smem + 32768 + Sb + gBq[nh][0] * 1024);
    gload16(wbase + koff + voffB[nh][1], smem + 32768 + Sb + gBq[nh][1] * 1024);
  };
  auto rdAf = [&](int Sb, int mh) {
#pragma unroll
    for (int mi = 0; mi < 2; ++mi) {
      af[mi][0] = *reinterpret_cast<const bf16x8*>(rdA[mh][0] + Sb + mi * 2048);
      af[mi][1] = *reinterpret_cast<const bf16x8*>(rdA[mh][1] + Sb + mi * 2048);
    }
  };
  auto rdBfA = [&](int Sb, int nh) {
#pragma unroll
    for (int ni = 0; ni < 2; ++ni) {
      bfA[ni][0] = *reinterpret_cast<const bf16x8*>(rdB[nh][0] + Sb + ni * 2048);
      bfA[ni][1] = *reinterpret_cast<const bf16x8*>(rdB[nh][1] + Sb + ni * 2048);
    }
  };
  auto rdBfB = [&](int Sb, int nh) {
#pragma unroll
    for (int ni = 0; ni < 2; ++ni) {
      bfB[ni][0] = *reinterpret_cast<const bf16x8*>(rdB[nh][0] + Sb + ni * 2048);
      bfB[ni][1] = *reinterpret_cast<const bf16x8*>(rdB[nh][1] + Sb + ni * 2048);
    }
  };
  auto mfmaQA = [&](int mh, int nh) {
#pragma unroll
    for (int mi = 0; mi < 2; ++mi)
#pragma unroll
      for (int ni = 0; ni < 2; ++ni)
#pragma unroll
        for (int ks = 0; ks < 2; ++ks)
          acc[mh * 2 + mi][nh * 2 + ni] =
              MFMA16(af[mi][ks], bfA[ni][ks], acc[mh * 2 + mi][nh * 2 + ni]);
  };
  auto mfmaQB = [&](int mh, int nh) {
#pragma unroll
    for (int mi = 0; mi < 2; ++mi)
#pragma unroll
      for (int ni = 0; ni < 2; ++ni)
#pragma unroll
        for (int ks = 0; ks < 2; ++ks)
          acc[mh * 2 + mi][nh * 2 + ni] =
              MFMA16(af[mi][ks], bfB[ni][ks], acc[mh * 2 + mi][nh * 2 + ni]);
  };

  // ---- prologue: t0 all 4 units + t1 {A0,B1,A1}; vmcnt(6) leaves t1's 3 in flight
  stA(0, 0, 0);
  stB(0, 1, 0);
  stA(0, 1, 0);
  stB(0, 0, 0);
  stA(16384, 0, 128);
  stB(16384, 1, 128);
  stA(16384, 1, 128);
  asm volatile("s_waitcnt vmcnt(6)" ::: "memory");
  __builtin_amdgcn_s_barrier();
  __builtin_amdgcn_sched_barrier(0);

  // ---- main loop: 6 iterations x 2 K-tiles, 8 phases each ----
  for (int i = 0; i < 6; ++i) {
    const bool nf = (i < 5);
    const unsigned kB1 = (unsigned)((2 * i + 1) * 128);
    const unsigned kA2 = (unsigned)((2 * i + 2) * 128);
    const unsigned kA3 = (unsigned)((2 * i + 3) * 128);

    // P1: tile even Q(0,0) [B0->bfA]; stage B0(odd)->S1
    rdAf(0, 0); rdBfA(0, 0); stB(16384, 0, kB1);
    MIDSYNC; mfmaQA(0, 0); ENDPH;
    // P2: Q(0,1) [B1->bfB]; stage A0(even+2)->S0
    rdBfB(0, 1); if (nf) stA(0, 0, kA2);
    MIDSYNC; mfmaQB(0, 1); ENDPH;
    // P3: Q(1,1) [A1]; stage B1(even+2)->S0
    rdAf(0, 1); if (nf) stB(0, 1, kA2);
    MIDSYNC; mfmaQB(1, 1); ENDPH;
    // P4: Q(1,0) [bfA held, no reads]; stage A1(even+2)->S0; counted vmcnt
    if (nf) stA(0, 1, kA2);
    MIDSYNC; mfmaQA(1, 0);
    if (nf) { ENDPH_VM6; } else { ENDPH_VM0; }
    // P5: tile odd Q(0,0); stage B0(even+2)->S0
    rdAf(16384, 0); rdBfA(16384, 0); if (nf) stB(0, 0, kA2);
    MIDSYNC; mfmaQA(0, 0); ENDPH;
    // P6: Q(0,1); stage A0(odd+2)->S1
    rdBfB(16384, 1); if (nf) stA(16384, 0, kA3);
    MIDSYNC; mfmaQB(0, 1); ENDPH;
    // P7: Q(1,1); stage B1(odd+2)->S1
    rdAf(16384, 1); if (nf) stB(16384, 1, kA3);
    MIDSYNC; mfmaQB(1, 1); ENDPH;
    // P8: Q(1,0); stage A1(odd+2)->S1; counted vmcnt
    if (nf) stA(16384, 1, kA3);
    MIDSYNC; mfmaQA(1, 0);
    if (nf) { ENDPH_VM6; } else { ENDPH_VM0; }
  }

  // ---- epilogue ----
  const int matrix = ntile / 6;  // 0=Q 1=K 2=V (128 | 768, no tile crosses)
  const float* bias = (matrix == 0) ? bq : ((matrix == 1) ? bk : bv);
  float bb[4];
#pragma unroll
  for (int ni = 0; ni < 4; ++ni)
    bb[ni] = bias[(ntile % 6) * 128 + wn * 64 + ni * 16 + (l & 15)];

  if (matrix == 2) {
    // V^T: acc -> LDS [n_local][m_local] bf16 (xor-swizzled, 256B rows),
    // then coalesced Vt[bh][96][640] writes (64 lanes -> 64 consecutive tokens).
#pragma unroll
    for (int mi = 0; mi < 4; ++mi)
#pragma unroll
      for (int ni = 0; ni < 4; ++ni) {
        const int n_local = wn * 64 + ni * 16 + (l & 15);
        const int m_base = wm * 64 + mi * 16 + (l >> 4) * 4;
#pragma unroll
        for (int r = 0; r < 4; r += 2) {
          const int m_local = m_base + r;
          const unsigned pk = (unsigned)f2bf(acc[mi][ni][r] + bb[ni]) |
                              ((unsigned)f2bf(acc[mi][ni][r + 1] + bb[ni]) << 16);
          const int byte = n_local * 256 + ((m_local * 2) ^ ((n_local & 15) << 3));
          *reinterpret_cast<unsigned*>(smem + byte) = pk;
        }
      }
    __syncthreads();
    const int nrow0 = w * 32;
    for (int rr = 0; rr < 32; ++rr) {
      const int n_local = nrow0 + rr;
      const int n_in = (ntile - 12) * 128 + n_local;
      const int h = n_in / 96, d = n_in - h * 96;
#pragma unroll
      for (int seg = 0; seg < 2; ++seg) {
        const int m_local = seg * 64 + l;
        const int byte = n_local * 256 + ((m_local * 2) ^ ((n_local & 15) << 3));
        const unsigned short val = *reinterpret_cast<unsigned short*>(smem + byte);
        const int m = mtile * 128 + m_local;
        if (m < kM) {
          const int b = m / 577, col = m - b * 577;
          Vt[((size_t)(b * 8 + h) * 96 + d) * 640 + col] = val;
        }
      }
    }
  } else {
    int hh[4], dd[4];
#pragma unroll
    for (int ni = 0; ni < 4; ++ni) {
      const int n_in = (ntile % 6) * 128 + wn * 64 + ni * 16 + (l & 15);
      hh[ni] = n_in / 96;
      dd[ni] = n_in - hh[ni] * 96;
    }
    unsigned short* dst = (matrix == 0) ? Q : K;
#pragma unroll
    for (int mi = 0; mi < 4; ++mi) {
#pragma unroll
      for (int r = 0; r < 4; ++r) {
        const int m = mtile * 128 + wm * 64 + mi * 16 + (l >> 4) * 4 + r;
        if (m >= kM) continue;
        const int bidx = m / 577;
        const int n = m - bidx * 577;
#pragma unroll
        for (int ni = 0; ni < 4; ++ni) {
          const float val = acc[mi][ni][r] + bb[ni];
          const size_t o = ((size_t)(bidx * 8 + hh[ni]) * 577 + n) * 96 + dd[ni];
          dst[o] = f2bf(val);
        }
      }
    }
  }
}

// ---------------- kernel 3: fused flash attention (8 waves, QBLK=128) ----------------
// Double-buffered K/V staging, counted vmcnt(4). No online max (logits bounded;
// fp32 exp/sum safe; bf16 P error is relative). P->bf16 via v_cvt_pk_bf16_f32.
__global__ __launch_bounds__(512, 4) void k_attn(
    const unsigned short* __restrict__ Q, const unsigned short* __restrict__ K,
    const unsigned short* __restrict__ Vt, float* __restrict__ out) {
  extern __shared__ char asmem[];  // buf0@0, buf1@28672 (K 16K, V@+16384 12K), sP@57344
  // XCD swizzle: 2560 blocks = 8 x 320; same-bh blocks land on one XCD
  int wk = blockIdx.x;
  {
    const int xcd = wk & 7, i = wk >> 3;
    wk = xcd * 320 + i;
  }
  const int bh = wk / 5, qt = wk - bh * 5;
  const int tid = threadIdx.x, w = tid >> 6, l = tid & 63;
  const int bb_ = bh >> 3, hh_ = bh & 7;
  const size_t hdbase = (size_t)bh * 577 * 96;
  char* const pS = asmem + 57344 + w * 2304;  // per-wave P: [16 q][72 bf16]

  const int qrow = qt * 128 + w * 16 + (l & 15);
  const int qn = (qrow > 576) ? 576 : qrow;

  bf16x8 fq[3];
#pragma unroll
  for (int ks = 0; ks < 3; ++ks) {
    const size_t off = hdbase + (size_t)qn * 96 + ks * 32 + (l >> 4) * 8;
    fq[ks] = *reinterpret_cast<const bf16x8*>(Q + off);
  }

  auto stage = [&](int kt, char* buf) {
    if (w < 7) {
#pragma unroll
      for (int i2 = 0; i2 < 4; ++i2) {
        const int j = w * 4 + i2;  // 0..27
        if (j < 16) {
          const int r = 4 * j + (l >> 4);
          const int lc = (l & 15) ^ (r & 7);
          const int lc2 = (lc < 12) ? lc : 11;
          int kvn = kt * 64 + r; if (kvn > 576) kvn = 576;
          gload16(K + hdbase + (size_t)kvn * 96 + lc2 * 8, buf + j * 1024);
        } else {
          const int u = j - 16;
          const int d = 8 * u + (l >> 3);
          const int lc = (l & 7) ^ (d & 7);
          gload16(Vt + (size_t)(bh * 96 + d) * 640 + kt * 64 + lc * 8,
                  buf + 16384 + u * 1024);
        }
      }
    }
  };

  f32x4 accO[6];
  const f32x4 fz = {0.f, 0.f, 0.f, 0.f};
#pragma unroll
  for (int i = 0; i < 6; ++i) accO[i] = fz;
  float lrun = 0.f;

  stage(0, asmem);

  for (int kt = 0; kt < 10; ++kt) {
    char* cur = asmem + (kt & 1) * 28672;
    if (kt < 9) {
      stage(kt + 1, asmem + ((kt + 1) & 1) * 28672);
      asm volatile("s_waitcnt vmcnt(4)" ::: "memory");
    } else {
      asm volatile("s_waitcnt vmcnt(0)" ::: "memory");
    }
    __builtin_amdgcn_s_barrier();
    __builtin_amdgcn_sched_barrier(0);

    // ---- S^T = K · Q^T ----
    f32x4 s_[4];
#pragma unroll
    for (int i = 0; i < 4; ++i) s_[i] = fz;
#pragma unroll
    for (int ks = 0; ks < 3; ++ks) {
#pragma unroll
      for (int af = 0; af < 4; ++af) {
        const int r = af * 16 + (l & 15);
        const int c16 = ((ks * 4) + (l >> 4)) ^ (r & 7);
        const bf16x8 kf = *reinterpret_cast<const bf16x8*>(cur + r * 256 + c16 * 16);
        s_[af] = MFMA16(kf, fq[ks], s_[af]);
      }
    }

    if (kt == 9) {  // mask kv >= 577
#pragma unroll
      for (int af = 0; af < 4; ++af) {
        const int kv0 = 576 + af * 16 + (l >> 4) * 4;
#pragma unroll
        for (int r = 0; r < 4; ++r)
          if (kv0 + r >= 577) s_[af][r] = -1e30f;
      }
    }

    // ---- P = exp(S); per-lane running sum; pack via v_cvt_pk_bf16_f32 ----
    float psum = 0.f;
    char* pbase = pS + (l & 15) * 144;
#pragma unroll
    for (int af = 0; af < 4; ++af) {
      const float p0 = __expf(s_[af][0]);
      const float p1 = __expf(s_[af][1]);
      const float p2 = __expf(s_[af][2]);
      const float p3 = __expf(s_[af][3]);
      psum += (p0 + p1) + (p2 + p3);
      unsigned w0, w1;
      asm("v_cvt_pk_bf16_f32 %0, %1, %2" : "=v"(w0) : "v"(p0), "v"(p1));
      asm("v_cvt_pk_bf16_f32 %0, %1, %2" : "=v"(w1) : "v"(p2), "v"(p3));
      uint2 ww; ww.x = w0; ww.y = w1;
      *reinterpret_cast<uint2*>(pbase + af * 32 + (l >> 4) * 8) = ww;
    }
    lrun += psum;
    // P is per-wave: lgkm drain orders ds_write -> ds_read within the wave
    asm volatile("s_waitcnt lgkmcnt(0)" ::: "memory");
    __builtin_amdgcn_sched_barrier(0);

    // ---- O^T += V^T · P^T ----
#pragma unroll
    for (int ks = 0; ks < 2; ++ks) {
      const bf16x8 pb = *reinterpret_cast<const bf16x8*>(
          pS + (l & 15) * 144 + ks * 64 + (l >> 4) * 16);
#pragma unroll
      for (int df = 0; df < 6; ++df) {
        const int r = df * 16 + (l & 15);
        const int c16 = ((ks * 4) + (l >> 4)) ^ (r & 7);
        const bf16x8 va = *reinterpret_cast<const bf16x8*>(
            cur + 16384 + r * 128 + c16 * 16);
        accO[df] = MFMA16(va, pb, accO[df]);
      }
    }
    // end barrier: all waves' reads of cur done before kt+1 stages overwrite it
    asm volatile("s_waitcnt lgkmcnt(0)" ::: "memory");
    __builtin_amdgcn_s_barrier();
    __builtin_amdgcn_sched_barrier(0);
  }

  // ---- epilogue: reduce l across the 4 lane-groups; out = O * scale / l ----
  lrun += __shfl_xor(lrun, 16, 64);
  lrun += __shfl_xor(lrun, 32, 64);
  if (qrow <= 576) {
    const float inv = kScale / lrun;
#pragma unroll
    for (int df = 0; df < 6; ++df) {
      float4 o;
      o.x = accO[df][0] * inv; o.y = accO[df][1] * inv;
      o.z = accO[df][2] * inv; o.w = accO[df][3] * inv;
      const size_t oo = ((size_t)bb_ * 577 + qrow) * 768 + hh_ * 96 + df * 16 + (l >> 4) * 4;
      *reinterpret_cast<float4*>(out + oo) = o;
    }
  }
}

extern "C" void kernel_launch(void* const* d_in, const int* in_sizes, int n_in,
                              void* d_out, int out_size, void* d_ws, size_t ws_size,
                              hipStream_t stream) {
  const float* x  = (const float*)d_in[0];
  const float* Wq = (const float*)d_in[1];
  const float* bq = (const float*)d_in[2];
  const float* Wk = (const float*)d_in[3];
  const float* bk = (const float*)d_in[4];
  const float* Wv = (const float*)d_in[5];
  const float* bv = (const float*)d_in[6];
  float* out = (float*)d_out;
  char* ws = (char*)d_ws;

  const size_t SZ = 56721408;  // 36928*768*2 bytes
  unsigned short* xh   = (unsigned short*)(ws);
  unsigned short* wcat = (unsigned short*)(ws + SZ);                    // 3538944 B
  unsigned short* Q    = (unsigned short*)(ws + SZ + 3538944);
  unsigned short* K    = (unsigned short*)(ws + 2 * SZ + 3538944);
  unsigned short* Vt   = (unsigned short*)(ws + 3 * SZ + 3538944);      // 62914560 B

  hipFuncSetAttribute((const void*)k_proj,
                      hipFuncAttributeMaxDynamicSharedMemorySize, 65536);
  hipFuncSetAttribute((const void*)k_attn,
                      hipFuncAttributeMaxDynamicSharedMemorySize, 75776);

  k_prep<<<34608, 256, 0, stream>>>(x, Wq, Wk, Wv, xh, wcat);
  k_proj<<<dim3(5202), 256, 65536, stream>>>(xh, wcat, bq, bk, bv, Q, K, Vt);
  k_attn<<<dim3(2560), 512, 75776, stream>>>(Q, K, Vt, out);
}

// Round 15
// 352.002 us; speedup vs baseline: 1.0238x; 1.0238x over previous
//
#include <hip/hip_runtime.h>
#include <stdint.h>

typedef __bf16 bf16x8 __attribute__((ext_vector_type(8)));
typedef float  f32x4  __attribute__((ext_vector_type(4)));

#define MFMA16(a, b, c) __builtin_amdgcn_mfma_f32_16x16x32_bf16((a), (b), (c), 0, 0, 0)

static constexpr int   kBz = 64, kNn = 577, kEe = 768, kHh = 8, kDd = 96;
static constexpr int   kM  = kBz * kNn;  // 36928 tokens
static constexpr float kScale = 0.10206207261596575f;  // 96^-0.5

__device__ __forceinline__ unsigned short f2bf(float f) {
  unsigned u = __float_as_uint(f);
  u += 0x7fffu + ((u >> 16) & 1u);  // RNE
  return (unsigned short)(u >> 16);
}
__device__ __forceinline__ float bf2f(unsigned short s) {
  return __uint_as_float(((unsigned)s) << 16);
}

__device__ __forceinline__ void gload16(const void* g, void* l) {
  __builtin_amdgcn_global_load_lds(
      (const __attribute__((address_space(1))) void*)(void*)g,
      (__attribute__((address_space(3))) void*)l, 16, 0, 0);
}

// ------ kernel 1: fused prep -- cast x to bf16 (blocks 0..27695) and build
// W^T bf16 [3*768 n][768 k] via 32x32 LDS transpose (blocks 27696..29423).
// The transpose fixes R13's stride-3072B W reads (~32x fetch amplification).
__global__ __launch_bounds__(256) void k_prep(const float* __restrict__ x,
                                              const float* __restrict__ Wq,
                                              const float* __restrict__ Wk,
                                              const float* __restrict__ Wv,
                                              unsigned short* __restrict__ xh,
                                              unsigned short* __restrict__ wcat) {
  __shared__ float Tw[32][33];
  const int b = blockIdx.x;
  if (b < 27696) {
    const int i = b * 256 + threadIdx.x;  // exact: 27696*256 == kM*kEe/4
    const float4 v = reinterpret_cast<const float4*>(x)[i];
    ushort4 h;
    h.x = f2bf(v.x); h.y = f2bf(v.y); h.z = f2bf(v.z); h.w = f2bf(v.w);
    reinterpret_cast<ushort4*>(xh)[i] = h;
  } else {
    // 1728 blocks: 3 mats x 24x24 tiles of 32x32
    const int b2 = b - 27696;
    const int mat = b2 / 576, t2 = b2 - mat * 576;
    const int k0 = (t2 / 24) * 32, n0 = (t2 - (t2 / 24) * 24) * 32;
    const float* W = (mat == 0) ? Wq : ((mat == 1) ? Wk : Wv);
    const int tr = threadIdx.x >> 5, tc = threadIdx.x & 31;  // 8 rows per pass
#pragma unroll
    for (int p = 0; p < 4; ++p) {
      const int k = k0 + p * 8 + tr;
      Tw[tc][p * 8 + tr] = W[(size_t)k * 768 + n0 + tc];  // coalesced 128B reads
    }
    __syncthreads();
#pragma unroll
    for (int p = 0; p < 4; ++p) {
      const int n = n0 + p * 8 + tr;
      wcat[(size_t)(mat * 768 + n) * 768 + k0 + tc] = f2bf(Tw[p * 8 + tr][tc]);
    }
  }
}

// ------- kernel 2: QKV projection GEMM, 128x128 tile, 4 waves, 8-phase -------
// (R13-exact: passed with bit-identical absmax)
#define MIDSYNC do { __builtin_amdgcn_s_barrier(); \
  asm volatile("s_waitcnt lgkmcnt(0)" ::: "memory"); \
  __builtin_amdgcn_sched_barrier(0); \
  __builtin_amdgcn_s_setprio(1); } while (0)
#define ENDPH do { __builtin_amdgcn_s_setprio(0); \
  __builtin_amdgcn_s_barrier(); \
  __builtin_amdgcn_sched_barrier(0); } while (0)
#define ENDPH_VM6 do { __builtin_amdgcn_s_setprio(0); \
  asm volatile("s_waitcnt vmcnt(6)" ::: "memory"); \
  __builtin_amdgcn_s_barrier(); \
  __builtin_amdgcn_sched_barrier(0); } while (0)
#define ENDPH_VM0 do { __builtin_amdgcn_s_setprio(0); \
  asm volatile("s_waitcnt vmcnt(0)" ::: "memory"); \
  __builtin_amdgcn_s_barrier(); \
  __builtin_amdgcn_sched_barrier(0); } while (0)

__global__ __launch_bounds__(256, 2) void k_proj(
    const unsigned short* __restrict__ xh, const unsigned short* __restrict__ wcat,
    const float* __restrict__ bq, const float* __restrict__ bk, const float* __restrict__ bv,
    unsigned short* __restrict__ Q, unsigned short* __restrict__ K,
    unsigned short* __restrict__ Vt) {
  extern __shared__ char smem[];  // 65536 B: A S0@0 S1@16384, B S0@32768 S1@49152
  const int tid = threadIdx.x, w = tid >> 6, l = tid & 63;
  const int wm = w >> 1, wn = w & 1;

  // bijective XCD swizzle: nwg=5202 = 8*650+2 -> q=650, r=2
  int bid = blockIdx.x;
  {
    const int xcd = bid & 7, i = bid >> 3;
    bid = ((xcd < 2) ? xcd * 651 : 2 * 651 + (xcd - 2) * 650) + i;
  }
  const int ntile = bid % 18, mtile = bid / 18;

  const int lrow8 = l >> 3;
  const int lc_sw = (l & 7) ^ lrow8;

  // stage slot ids matching interleaved read halves:
  // half 0 = slots {0,1,2,3, 8,9,10,11}; half 1 = +4.
  const int p0 = 2 * w, p1 = 2 * w + 1;
  int gAq[2][2], gBq[2][2];
  gAq[0][0] = (p0 >> 2) * 8 + (p0 & 3);
  gAq[0][1] = (p1 >> 2) * 8 + (p1 & 3);
  gAq[1][0] = gAq[0][0] + 4;
  gAq[1][1] = gAq[0][1] + 4;
  gBq[0][0] = gAq[0][0];
  gBq[0][1] = gAq[0][1];
  gBq[1][0] = gAq[1][0];
  gBq[1][1] = gAq[1][1];

  // hoisted global byte-voffsets
  unsigned voffA[2][2], voffB[2][2];
#pragma unroll
  for (int h = 0; h < 2; ++h)
#pragma unroll
    for (int j = 0; j < 2; ++j) {
      int m = mtile * 128 + 8 * gAq[h][j] + lrow8;
      if (m > kM - 1) m = kM - 1;
      voffA[h][j] = (unsigned)(m * 1536 + lc_sw * 16);
      const int bn = ntile * 128 + 8 * gBq[h][j] + lrow8;
      voffB[h][j] = (unsigned)(bn * 1536 + lc_sw * 16);
    }

  // hoisted LDS read base pointers [half][ks]
  const char* rdA[2][2];
  const char* rdB[2][2];
#pragma unroll
  for (int ks = 0; ks < 2; ++ks) {
    const int cks = (((ks * 4) + (l >> 4)) ^ (l & 7)) * 16;
#pragma unroll
    for (int h = 0; h < 2; ++h) {
      rdA[h][ks] = smem + (wm * 64 + h * 32 + (l & 15)) * 128 + cks;
      rdB[h][ks] = smem + 32768 + (wn * 64 + h * 32 + (l & 15)) * 128 + cks;
    }
  }

  const char* xbase = (const char*)xh;
  const char* wbase = (const char*)wcat;

  f32x4 acc[4][4];
  const f32x4 fz = {0.f, 0.f, 0.f, 0.f};
#pragma unroll
  for (int i = 0; i < 4; ++i)
#pragma unroll
    for (int j = 0; j < 4; ++j) acc[i][j] = fz;

  bf16x8 af[2][2], bfA[2][2], bfB[2][2];

  auto stA = [&](int Sb, int mh, unsigned koff) {
    gload16(xbase + koff + voffA[mh][0], smem + Sb + gAq[mh][0] * 1024);
    gload16(xbase + koff + voffA[mh][1], smem + Sb + gAq[mh][1] * 1024);
  };
  auto stB = [&](int Sb, int nh, unsigned koff) {
    gload16(wbase + koff + voffB[nh][0], smem + 32768 + Sb + gBq[nh][0] * 1024);
    gload16(wbase + koff + voffB[nh][1], smem + 32768 + Sb + gBq[nh][1] * 1024);
  };
  auto rdAf = [&](int Sb, int mh) {
#pragma unroll
    for (int mi = 0; mi < 2; ++mi) {
      af[mi][0] = *reinterpret_cast<const bf16x8*>(rdA[mh][0] + Sb + mi * 2048);
      af[mi][1] = *reinterpret_cast<const bf16x8*>(rdA[mh][1] + Sb + mi * 2048);
    }
  };
  auto rdBfA = [&](int Sb, int nh) {
#pragma unroll
    for (int ni = 0; ni < 2; ++ni) {
      bfA[ni][0] = *reinterpret_cast<const bf16x8*>(rdB[nh][0] + Sb + ni * 2048);
      bfA[ni][1] = *reinterpret_cast<const bf16x8*>(rdB[nh][1] + Sb + ni * 2048);
    }
  };
  auto rdBfB = [&](int Sb, int nh) {
#pragma unroll
    for (int ni = 0; ni < 2; ++ni) {
      bfB[ni][0] = *reinterpret_cast<const bf16x8*>(rdB[nh][0] + Sb + ni * 2048);
      bfB[ni][1] = *reinterpret_cast<const bf16x8*>(rdB[nh][1] + Sb + ni * 2048);
    }
  };
  auto mfmaQA = [&](int mh, int nh) {
#pragma unroll
    for (int mi = 0; mi < 2; ++mi)
#pragma unroll
      for (int ni = 0; ni < 2; ++ni)
#pragma unroll
        for (int ks = 0; ks < 2; ++ks)
          acc[mh * 2 + mi][nh * 2 + ni] =
              MFMA16(af[mi][ks], bfA[ni][ks], acc[mh * 2 + mi][nh * 2 + ni]);
  };
  auto mfmaQB = [&](int mh, int nh) {
#pragma unroll
    for (int mi = 0; mi < 2; ++mi)
#pragma unroll
      for (int ni = 0; ni < 2; ++ni)
#pragma unroll
        for (int ks = 0; ks < 2; ++ks)
          acc[mh * 2 + mi][nh * 2 + ni] =
              MFMA16(af[mi][ks], bfB[ni][ks], acc[mh * 2 + mi][nh * 2 + ni]);
  };

  // ---- prologue: t0 all 4 units + t1 {A0,B1,A1}; vmcnt(6) leaves t1's 3 in flight
  stA(0, 0, 0);
  stB(0, 1, 0);
  stA(0, 1, 0);
  stB(0, 0, 0);
  stA(16384, 0, 128);
  stB(16384, 1, 128);
  stA(16384, 1, 128);
  asm volatile("s_waitcnt vmcnt(6)" ::: "memory");
  __builtin_amdgcn_s_barrier();
  __builtin_amdgcn_sched_barrier(0);

  // ---- main loop: 6 iterations x 2 K-tiles, 8 phases each ----
  for (int i = 0; i < 6; ++i) {
    const bool nf = (i < 5);
    const unsigned kB1 = (unsigned)((2 * i + 1) * 128);
    const unsigned kA2 = (unsigned)((2 * i + 2) * 128);
    const unsigned kA3 = (unsigned)((2 * i + 3) * 128);

    // P1: tile even Q(0,0) [B0->bfA]; stage B0(odd)->S1
    rdAf(0, 0); rdBfA(0, 0); stB(16384, 0, kB1);
    MIDSYNC; mfmaQA(0, 0); ENDPH;
    // P2: Q(0,1) [B1->bfB]; stage A0(even+2)->S0
    rdBfB(0, 1); if (nf) stA(0, 0, kA2);
    MIDSYNC; mfmaQB(0, 1); ENDPH;
    // P3: Q(1,1) [A1]; stage B1(even+2)->S0
    rdAf(0, 1); if (nf) stB(0, 1, kA2);
    MIDSYNC; mfmaQB(1, 1); ENDPH;
    // P4: Q(1,0) [bfA held, no reads]; stage A1(even+2)->S0; counted vmcnt
    if (nf) stA(0, 1, kA2);
    MIDSYNC; mfmaQA(1, 0);
    if (nf) { ENDPH_VM6; } else { ENDPH_VM0; }
    // P5: tile odd Q(0,0); stage B0(even+2)->S0
    rdAf(16384, 0); rdBfA(16384, 0); if (nf) stB(0, 0, kA2);
    MIDSYNC; mfmaQA(0, 0); ENDPH;
    // P6: Q(0,1); stage A0(odd+2)->S1
    rdBfB(16384, 1); if (nf) stA(16384, 0, kA3);
    MIDSYNC; mfmaQB(0, 1); ENDPH;
    // P7: Q(1,1); stage B1(odd+2)->S1
    rdAf(16384, 1); if (nf) stB(16384, 1, kA3);
    MIDSYNC; mfmaQB(1, 1); ENDPH;
    // P8: Q(1,0); stage A1(odd+2)->S1; counted vmcnt
    if (nf) stA(16384, 1, kA3);
    MIDSYNC; mfmaQA(1, 0);
    if (nf) { ENDPH_VM6; } else { ENDPH_VM0; }
  }

  // ---- epilogue ----
  const int matrix = ntile / 6;  // 0=Q 1=K 2=V (128 | 768, no tile crosses)
  const float* bias = (matrix == 0) ? bq : ((matrix == 1) ? bk : bv);
  float bb[4];
#pragma unroll
  for (int ni = 0; ni < 4; ++ni)
    bb[ni] = bias[(ntile % 6) * 128 + wn * 64 + ni * 16 + (l & 15)];

  if (matrix == 2) {
    // V^T: acc -> LDS [n_local][m_local] bf16 (xor-swizzled, 256B rows),
    // then coalesced Vt[bh][96][640] writes (64 lanes -> 64 consecutive tokens).
#pragma unroll
    for (int mi = 0; mi < 4; ++mi)
#pragma unroll
      for (int ni = 0; ni < 4; ++ni) {
        const int n_local = wn * 64 + ni * 16 + (l & 15);
        const int m_base = wm * 64 + mi * 16 + (l >> 4) * 4;
#pragma unroll
        for (int r = 0; r < 4; r += 2) {
          const int m_local = m_base + r;
          const unsigned pk = (unsigned)f2bf(acc[mi][ni][r] + bb[ni]) |
                              ((unsigned)f2bf(acc[mi][ni][r + 1] + bb[ni]) << 16);
          const int byte = n_local * 256 + ((m_local * 2) ^ ((n_local & 15) << 3));
          *reinterpret_cast<unsigned*>(smem + byte) = pk;
        }
      }
    __syncthreads();
    const int nrow0 = w * 32;
    for (int rr = 0; rr < 32; ++rr) {
      const int n_local = nrow0 + rr;
      const int n_in = (ntile - 12) * 128 + n_local;
      const int h = n_in / 96, d = n_in - h * 96;
#pragma unroll
      for (int seg = 0; seg < 2; ++seg) {
        const int m_local = seg * 64 + l;
        const int byte = n_local * 256 + ((m_local * 2) ^ ((n_local & 15) << 3));
        const unsigned short val = *reinterpret_cast<unsigned short*>(smem + byte);
        const int m = mtile * 128 + m_local;
        if (m < kM) {
          const int b = m / 577, col = m - b * 577;
          Vt[((size_t)(b * 8 + h) * 96 + d) * 640 + col] = val;
        }
      }
    }
  } else {
    int hh[4], dd[4];
#pragma unroll
    for (int ni = 0; ni < 4; ++ni) {
      const int n_in = (ntile % 6) * 128 + wn * 64 + ni * 16 + (l & 15);
      hh[ni] = n_in / 96;
      dd[ni] = n_in - hh[ni] * 96;
    }
    unsigned short* dst = (matrix == 0) ? Q : K;
#pragma unroll
    for (int mi = 0; mi < 4; ++mi) {
#pragma unroll
      for (int r = 0; r < 4; ++r) {
        const int m = mtile * 128 + wm * 64 + mi * 16 + (l >> 4) * 4 + r;
        if (m >= kM) continue;
        const int bidx = m / 577;
        const int n = m - bidx * 577;
#pragma unroll
        for (int ni = 0; ni < 4; ++ni) {
          const float val = acc[mi][ni][r] + bb[ni];
          const size_t o = ((size_t)(bidx * 8 + hh[ni]) * 577 + n) * 96 + dd[ni];
          dst[o] = f2bf(val);
        }
      }
    }
  }
}

// ---------------- kernel 3: fused flash attention (8 waves, QBLK=128) ----------------
// (R13-exact known-good version: double-buffered K/V staging, counted vmcnt(4),
// no online max, P->bf16 via v_cvt_pk_bf16_f32.)
__global__ __launch_bounds__(512, 4) void k_attn(
    const unsigned short* __restrict__ Q, const unsigned short* __restrict__ K,
    const unsigned short* __restrict__ Vt, float* __restrict__ out) {
  extern __shared__ char asmem[];  // buf0@0, buf1@28672 (K 16K, V@+16384 12K), sP@57344
  // XCD swizzle: 2560 blocks = 8 x 320; same-bh blocks land on one XCD
  int wk = blockIdx.x;
  {
    const int xcd = wk & 7, i = wk >> 3;
    wk = xcd * 320 + i;
  }
  const int bh = wk / 5, qt = wk - bh * 5;
  const int tid = threadIdx.x, w = tid >> 6, l = tid & 63;
  const int bb_ = bh >> 3, hh_ = bh & 7;
  const size_t hdbase = (size_t)bh * 577 * 96;
  char* const pS = asmem + 57344 + w * 2304;  // per-wave P: [16 q][72 bf16]

  const int qrow = qt * 128 + w * 16 + (l & 15);
  const int qn = (qrow > 576) ? 576 : qrow;

  bf16x8 fq[3];
#pragma unroll
  for (int ks = 0; ks < 3; ++ks) {
    const size_t off = hdbase + (size_t)qn * 96 + ks * 32 + (l >> 4) * 8;
    fq[ks] = *reinterpret_cast<const bf16x8*>(Q + off);
  }

  auto stage = [&](int kt, char* buf) {
    if (w < 7) {
#pragma unroll
      for (int i2 = 0; i2 < 4; ++i2) {
        const int j = w * 4 + i2;  // 0..27
        if (j < 16) {
          const int r = 4 * j + (l >> 4);
          const int lc = (l & 15) ^ (r & 7);
          const int lc2 = (lc < 12) ? lc : 11;
          int kvn = kt * 64 + r; if (kvn > 576) kvn = 576;
          gload16(K + hdbase + (size_t)kvn * 96 + lc2 * 8, buf + j * 1024);
        } else {
          const int u = j - 16;
          const int d = 8 * u + (l >> 3);
          const int lc = (l & 7) ^ (d & 7);
          gload16(Vt + (size_t)(bh * 96 + d) * 640 + kt * 64 + lc * 8,
                  buf + 16384 + u * 1024);
        }
      }
    }
  };

  f32x4 accO[6];
  const f32x4 fz = {0.f, 0.f, 0.f, 0.f};
#pragma unroll
  for (int i = 0; i < 6; ++i) accO[i] = fz;
  float lrun = 0.f;

  stage(0, asmem);

  for (int kt = 0; kt < 10; ++kt) {
    char* cur = asmem + (kt & 1) * 28672;
    if (kt < 9) {
      stage(kt + 1, asmem + ((kt + 1) & 1) * 28672);
      asm volatile("s_waitcnt vmcnt(4)" ::: "memory");
    } else {
      asm volatile("s_waitcnt vmcnt(0)" ::: "memory");
    }
    __builtin_amdgcn_s_barrier();
    __builtin_amdgcn_sched_barrier(0);

    // ---- S^T = K · Q^T ----
    f32x4 s_[4];
#pragma unroll
    for (int i = 0; i < 4; ++i) s_[i] = fz;
#pragma unroll
    for (int ks = 0; ks < 3; ++ks) {
#pragma unroll
      for (int af = 0; af < 4; ++af) {
        const int r = af * 16 + (l & 15);
        const int c16 = ((ks * 4) + (l >> 4)) ^ (r & 7);
        const bf16x8 kf = *reinterpret_cast<const bf16x8*>(cur + r * 256 + c16 * 16);
        s_[af] = MFMA16(kf, fq[ks], s_[af]);
      }
    }

    if (kt == 9) {  // mask kv >= 577
#pragma unroll
      for (int af = 0; af < 4; ++af) {
        const int kv0 = 576 + af * 16 + (l >> 4) * 4;
#pragma unroll
        for (int r = 0; r < 4; ++r)
          if (kv0 + r >= 577) s_[af][r] = -1e30f;
      }
    }

    // ---- P = exp(S); per-lane running sum; pack via v_cvt_pk_bf16_f32 ----
    float psum = 0.f;
    char* pbase = pS + (l & 15) * 144;
#pragma unroll
    for (int af = 0; af < 4; ++af) {
      const float p0 = __expf(s_[af][0]);
      const float p1 = __expf(s_[af][1]);
      const float p2 = __expf(s_[af][2]);
      const float p3 = __expf(s_[af][3]);
      psum += (p0 + p1) + (p2 + p3);
      unsigned w0, w1;
      asm("v_cvt_pk_bf16_f32 %0, %1, %2" : "=v"(w0) : "v"(p0), "v"(p1));
      asm("v_cvt_pk_bf16_f32 %0, %1, %2" : "=v"(w1) : "v"(p2), "v"(p3));
      uint2 ww; ww.x = w0; ww.y = w1;
      *reinterpret_cast<uint2*>(pbase + af * 32 + (l >> 4) * 8) = ww;
    }
    lrun += psum;
    // P is per-wave: lgkm drain orders ds_write -> ds_read within the wave
    asm volatile("s_waitcnt lgkmcnt(0)" ::: "memory");
    __builtin_amdgcn_sched_barrier(0);

    // ---- O^T += V^T · P^T ----
#pragma unroll
    for (int ks = 0; ks < 2; ++ks) {
      const bf16x8 pb = *reinterpret_cast<const bf16x8*>(
          pS + (l & 15) * 144 + ks * 64 + (l >> 4) * 16);
#pragma unroll
      for (int df = 0; df < 6; ++df) {
        const int r = df * 16 + (l & 15);
        const int c16 = ((ks * 4) + (l >> 4)) ^ (r & 7);
        const bf16x8 va = *reinterpret_cast<const bf16x8*>(
            cur + 16384 + r * 128 + c16 * 16);
        accO[df] = MFMA16(va, pb, accO[df]);
      }
    }
    // end barrier: all waves' reads of cur done before kt+1 stages overwrite it
    asm volatile("s_waitcnt lgkmcnt(0)" ::: "memory");
    __builtin_amdgcn_s_barrier();
    __builtin_amdgcn_sched_barrier(0);
  }

  // ---- epilogue: reduce l across the 4 lane-groups; out = O * scale / l ----
  lrun += __shfl_xor(lrun, 16, 64);
  lrun += __shfl_xor(lrun, 32, 64);
  if (qrow <= 576) {
    const float inv = kScale / lrun;
#pragma unroll
    for (int df = 0; df < 6; ++df) {
      float4 o;
      o.x = accO[df][0] * inv; o.y = accO[df][1] * inv;
      o.z = accO[df][2] * inv; o.w = accO[df][3] * inv;
      const size_t oo = ((size_t)bb_ * 577 + qrow) * 768 + hh_ * 96 + df * 16 + (l >> 4) * 4;
      *reinterpret_cast<float4*>(out + oo) = o;
    }
  }
}

extern "C" void kernel_launch(void* const* d_in, const int* in_sizes, int n_in,
                              void* d_out, int out_size, void* d_ws, size_t ws_size,
                              hipStream_t stream) {
  const float* x  = (const float*)d_in[0];
  const float* Wq = (const float*)d_in[1];
  const float* bq = (const float*)d_in[2];
  const float* Wk = (const float*)d_in[3];
  const float* bk = (const float*)d_in[4];
  const float* Wv = (const float*)d_in[5];
  const float* bv = (const float*)d_in[6];
  float* out = (float*)d_out;
  char* ws = (char*)d_ws;

  const size_t SZ = 56721408;  // 36928*768*2 bytes
  unsigned short* xh   = (unsigned short*)(ws);
  unsigned short* wcat = (unsigned short*)(ws + SZ);                    // 3538944 B
  unsigned short* Q    = (unsigned short*)(ws + SZ + 3538944);
  unsigned short* K    = (unsigned short*)(ws + 2 * SZ + 3538944);
  unsigned short* Vt   = (unsigned short*)(ws + 3 * SZ + 3538944);      // 62914560 B

  hipFuncSetAttribute((const void*)k_proj,
                      hipFuncAttributeMaxDynamicSharedMemorySize, 65536);
  hipFuncSetAttribute((const void*)k_attn,
                      hipFuncAttributeMaxDynamicSharedMemorySize, 75776);

  k_prep<<<29424, 256, 0, stream>>>(x, Wq, Wk, Wv, xh, wcat);
  k_proj<<<dim3(5202), 256, 65536, stream>>>(xh, wcat, bq, bk, bv, Q, K, Vt);
  k_attn<<<dim3(2560), 512, 75776, stream>>>(Q, K, Vt, out);
}

// Round 17
// 350.424 us; speedup vs baseline: 1.0284x; 1.0045x over previous
//
#include <hip/hip_runtime.h>
#include <stdint.h>

typedef __bf16 bf16x8 __attribute__((ext_vector_type(8)));
typedef float  f32x4  __attribute__((ext_vector_type(4)));

#define MFMA16(a, b, c) __builtin_amdgcn_mfma_f32_16x16x32_bf16((a), (b), (c), 0, 0, 0)

static constexpr int   kBz = 64, kNn = 577, kEe = 768, kHh = 8, kDd = 96;
static constexpr int   kM  = kBz * kNn;  // 36928 tokens
static constexpr float kScale = 0.10206207261596575f;  // 96^-0.5

__device__ __forceinline__ unsigned short f2bf(float f) {
  unsigned u = __float_as_uint(f);
  u += 0x7fffu + ((u >> 16) & 1u);  // RNE
  return (unsigned short)(u >> 16);
}
__device__ __forceinline__ float bf2f(unsigned short s) {
  return __uint_as_float(((unsigned)s) << 16);
}

__device__ __forceinline__ void gload16(const void* g, void* l) {
  __builtin_amdgcn_global_load_lds(
      (const __attribute__((address_space(1))) void*)(void*)g,
      (__attribute__((address_space(3))) void*)l, 16, 0, 0);
}

// ------ kernel 1: fused prep -- cast x to bf16 (blocks 0..27695) and build
// W^T bf16 [3*768 n][768 k] via 32x32 LDS transpose (blocks 27696..29423). ------
__global__ __launch_bounds__(256) void k_prep(const float* __restrict__ x,
                                              const float* __restrict__ Wq,
                                              const float* __restrict__ Wk,
                                              const float* __restrict__ Wv,
                                              unsigned short* __restrict__ xh,
                                              unsigned short* __restrict__ wcat) {
  __shared__ float Tw[32][33];
  const int b = blockIdx.x;
  if (b < 27696) {
    const int i = b * 256 + threadIdx.x;  // exact: 27696*256 == kM*kEe/4
    const float4 v = reinterpret_cast<const float4*>(x)[i];
    ushort4 h;
    h.x = f2bf(v.x); h.y = f2bf(v.y); h.z = f2bf(v.z); h.w = f2bf(v.w);
    reinterpret_cast<ushort4*>(xh)[i] = h;
  } else {
    // 1728 blocks: 3 mats x 24x24 tiles of 32x32
    const int b2 = b - 27696;
    const int mat = b2 / 576, t2 = b2 - mat * 576;
    const int k0 = (t2 / 24) * 32, n0 = (t2 - (t2 / 24) * 24) * 32;
    const float* W = (mat == 0) ? Wq : ((mat == 1) ? Wk : Wv);
    const int tr = threadIdx.x >> 5, tc = threadIdx.x & 31;  // 8 rows per pass
#pragma unroll
    for (int p = 0; p < 4; ++p) {
      const int k = k0 + p * 8 + tr;
      Tw[tc][p * 8 + tr] = W[(size_t)k * 768 + n0 + tc];  // coalesced 128B reads
    }
    __syncthreads();
#pragma unroll
    for (int p = 0; p < 4; ++p) {
      const int n = n0 + p * 8 + tr;
      wcat[(size_t)(mat * 768 + n) * 768 + k0 + tc] = f2bf(Tw[p * 8 + tr][tc]);
    }
  }
}

// ------- kernel 2: QKV projection GEMM, 128x128 tile, 4 waves, 8-phase -------
// (R13-exact: passed with bit-identical absmax)
#define MIDSYNC do { __builtin_amdgcn_s_barrier(); \
  asm volatile("s_waitcnt lgkmcnt(0)" ::: "memory"); \
  __builtin_amdgcn_sched_barrier(0); \
  __builtin_amdgcn_s_setprio(1); } while (0)
#define ENDPH do { __builtin_amdgcn_s_setprio(0); \
  __builtin_amdgcn_s_barrier(); \
  __builtin_amdgcn_sched_barrier(0); } while (0)
#define ENDPH_VM6 do { __builtin_amdgcn_s_setprio(0); \
  asm volatile("s_waitcnt vmcnt(6)" ::: "memory"); \
  __builtin_amdgcn_s_barrier(); \
  __builtin_amdgcn_sched_barrier(0); } while (0)
#define ENDPH_VM0 do { __builtin_amdgcn_s_setprio(0); \
  asm volatile("s_waitcnt vmcnt(0)" ::: "memory"); \
  __builtin_amdgcn_s_barrier(); \
  __builtin_amdgcn_sched_barrier(0); } while (0)

__global__ __launch_bounds__(256, 2) void k_proj(
    const unsigned short* __restrict__ xh, const unsigned short* __restrict__ wcat,
    const float* __restrict__ bq, const float* __restrict__ bk, const float* __restrict__ bv,
    unsigned short* __restrict__ Q, unsigned short* __restrict__ K,
    unsigned short* __restrict__ Vt) {
  extern __shared__ char smem[];  // 65536 B: A S0@0 S1@16384, B S0@32768 S1@49152
  const int tid = threadIdx.x, w = tid >> 6, l = tid & 63;
  const int wm = w >> 1, wn = w & 1;

  // bijective XCD swizzle: nwg=5202 = 8*650+2 -> q=650, r=2
  int bid = blockIdx.x;
  {
    const int xcd = bid & 7, i = bid >> 3;
    bid = ((xcd < 2) ? xcd * 651 : 2 * 651 + (xcd - 2) * 650) + i;
  }
  const int ntile = bid % 18, mtile = bid / 18;

  const int lrow8 = l >> 3;
  const int lc_sw = (l & 7) ^ lrow8;

  // stage slot ids matching interleaved read halves:
  // half 0 = slots {0,1,2,3, 8,9,10,11}; half 1 = +4.
  const int p0 = 2 * w, p1 = 2 * w + 1;
  int gAq[2][2], gBq[2][2];
  gAq[0][0] = (p0 >> 2) * 8 + (p0 & 3);
  gAq[0][1] = (p1 >> 2) * 8 + (p1 & 3);
  gAq[1][0] = gAq[0][0] + 4;
  gAq[1][1] = gAq[0][1] + 4;
  gBq[0][0] = gAq[0][0];
  gBq[0][1] = gAq[0][1];
  gBq[1][0] = gAq[1][0];
  gBq[1][1] = gAq[1][1];

  // hoisted global byte-voffsets
  unsigned voffA[2][2], voffB[2][2];
#pragma unroll
  for (int h = 0; h < 2; ++h)
#pragma unroll
    for (int j = 0; j < 2; ++j) {
      int m = mtile * 128 + 8 * gAq[h][j] + lrow8;
      if (m > kM - 1) m = kM - 1;
      voffA[h][j] = (unsigned)(m * 1536 + lc_sw * 16);
      const int bn = ntile * 128 + 8 * gBq[h][j] + lrow8;
      voffB[h][j] = (unsigned)(bn * 1536 + lc_sw * 16);
    }

  // hoisted LDS read base pointers [half][ks]
  const char* rdA[2][2];
  const char* rdB[2][2];
#pragma unroll
  for (int ks = 0; ks < 2; ++ks) {
    const int cks = (((ks * 4) + (l >> 4)) ^ (l & 7)) * 16;
#pragma unroll
    for (int h = 0; h < 2; ++h) {
      rdA[h][ks] = smem + (wm * 64 + h * 32 + (l & 15)) * 128 + cks;
      rdB[h][ks] = smem + 32768 + (wn * 64 + h * 32 + (l & 15)) * 128 + cks;
    }
  }

  const char* xbase = (const char*)xh;
  const char* wbase = (const char*)wcat;

  f32x4 acc[4][4];
  const f32x4 fz = {0.f, 0.f, 0.f, 0.f};
#pragma unroll
  for (int i = 0; i < 4; ++i)
#pragma unroll
    for (int j = 0; j < 4; ++j) acc[i][j] = fz;

  bf16x8 af[2][2], bfA[2][2], bfB[2][2];

  auto stA = [&](int Sb, int mh, unsigned koff) {
    gload16(xbase + koff + voffA[mh][0], smem + Sb + gAq[mh][0] * 1024);
    gload16(xbase + koff + voffA[mh][1], smem + Sb + gAq[mh][1] * 1024);
  };
  auto stB = [&](int Sb, int nh, unsigned koff) {
    gload16(wbase + koff + voffB[nh][0], smem + 32768 + Sb + gBq[nh][0] * 1024);
    gload16(wbase + koff + voffB[nh][1], smem + 32768 + Sb + gBq[nh][1] * 1024);
  };
  auto rdAf = [&](int Sb, int mh) {
#pragma unroll
    for (int mi = 0; mi < 2; ++mi) {
      af[mi][0] = *reinterpret_cast<const bf16x8*>(rdA[mh][0] + Sb + mi * 2048);
      af[mi][1] = *reinterpret_cast<const bf16x8*>(rdA[mh][1] + Sb + mi * 2048);
    }
  };
  auto rdBfA = [&](int Sb, int nh) {
#pragma unroll
    for (int ni = 0; ni < 2; ++ni) {
      bfA[ni][0] = *reinterpret_cast<const bf16x8*>(rdB[nh][0] + Sb + ni * 2048);
      bfA[ni][1] = *reinterpret_cast<const bf16x8*>(rdB[nh][1] + Sb + ni * 2048);
    }
  };
  auto rdBfB = [&](int Sb, int nh) {
#pragma unroll
    for (int ni = 0; ni < 2; ++ni) {
      bfB[ni][0] = *reinterpret_cast<const bf16x8*>(rdB[nh][0] + Sb + ni * 2048);
      bfB[ni][1] = *reinterpret_cast<const bf16x8*>(rdB[nh][1] + Sb + ni * 2048);
    }
  };
  auto mfmaQA = [&](int mh, int nh) {
#pragma unroll
    for (int mi = 0; mi < 2; ++mi)
#pragma unroll
      for (int ni = 0; ni < 2; ++ni)
#pragma unroll
        for (int ks = 0; ks < 2; ++ks)
          acc[mh * 2 + mi][nh * 2 + ni] =
              MFMA16(af[mi][ks], bfA[ni][ks], acc[mh * 2 + mi][nh * 2 + ni]);
  };
  auto mfmaQB = [&](int mh, int nh) {
#pragma unroll
    for (int mi = 0; mi < 2; ++mi)
#pragma unroll
      for (int ni = 0; ni < 2; ++ni)
#pragma unroll
        for (int ks = 0; ks < 2; ++ks)
          acc[mh * 2 + mi][nh * 2 + ni] =
              MFMA16(af[mi][ks], bfB[ni][ks], acc[mh * 2 + mi][nh * 2 + ni]);
  };

  // ---- prologue: t0 all 4 units + t1 {A0,B1,A1}; vmcnt(6) leaves t1's 3 in flight
  stA(0, 0, 0);
  stB(0, 1, 0);
  stA(0, 1, 0);
  stB(0, 0, 0);
  stA(16384, 0, 128);
  stB(16384, 1, 128);
  stA(16384, 1, 128);
  asm volatile("s_waitcnt vmcnt(6)" ::: "memory");
  __builtin_amdgcn_s_barrier();
  __builtin_amdgcn_sched_barrier(0);

  // ---- main loop: 6 iterations x 2 K-tiles, 8 phases each ----
  for (int i = 0; i < 6; ++i) {
    const bool nf = (i < 5);
    const unsigned kB1 = (unsigned)((2 * i + 1) * 128);
    const unsigned kA2 = (unsigned)((2 * i + 2) * 128);
    const unsigned kA3 = (unsigned)((2 * i + 3) * 128);

    // P1: tile even Q(0,0) [B0->bfA]; stage B0(odd)->S1
    rdAf(0, 0); rdBfA(0, 0); stB(16384, 0, kB1);
    MIDSYNC; mfmaQA(0, 0); ENDPH;
    // P2: Q(0,1) [B1->bfB]; stage A0(even+2)->S0
    rdBfB(0, 1); if (nf) stA(0, 0, kA2);
    MIDSYNC; mfmaQB(0, 1); ENDPH;
    // P3: Q(1,1) [A1]; stage B1(even+2)->S0
    rdAf(0, 1); if (nf) stB(0, 1, kA2);
    MIDSYNC; mfmaQB(1, 1); ENDPH;
    // P4: Q(1,0) [bfA held, no reads]; stage A1(even+2)->S0; counted vmcnt
    if (nf) stA(0, 1, kA2);
    MIDSYNC; mfmaQA(1, 0);
    if (nf) { ENDPH_VM6; } else { ENDPH_VM0; }
    // P5: tile odd Q(0,0); stage B0(even+2)->S0
    rdAf(16384, 0); rdBfA(16384, 0); if (nf) stB(0, 0, kA2);
    MIDSYNC; mfmaQA(0, 0); ENDPH;
    // P6: Q(0,1); stage A0(odd+2)->S1
    rdBfB(16384, 1); if (nf) stA(16384, 0, kA3);
    MIDSYNC; mfmaQB(0, 1); ENDPH;
    // P7: Q(1,1); stage B1(odd+2)->S1
    rdAf(16384, 1); if (nf) stB(16384, 1, kA3);
    MIDSYNC; mfmaQB(1, 1); ENDPH;
    // P8: Q(1,0); stage A1(odd+2)->S1; counted vmcnt
    if (nf) stA(16384, 1, kA3);
    MIDSYNC; mfmaQA(1, 0);
    if (nf) { ENDPH_VM6; } else { ENDPH_VM0; }
  }

  // ---- epilogue ----
  const int matrix = ntile / 6;  // 0=Q 1=K 2=V (128 | 768, no tile crosses)
  const float* bias = (matrix == 0) ? bq : ((matrix == 1) ? bk : bv);
  float bb[4];
#pragma unroll
  for (int ni = 0; ni < 4; ++ni)
    bb[ni] = bias[(ntile % 6) * 128 + wn * 64 + ni * 16 + (l & 15)];

  if (matrix == 2) {
    // V^T: acc -> LDS [n_local][m_local] bf16 (xor-swizzled, 256B rows),
    // then coalesced Vt[bh][96][640] writes (64 lanes -> 64 consecutive tokens).
#pragma unroll
    for (int mi = 0; mi < 4; ++mi)
#pragma unroll
      for (int ni = 0; ni < 4; ++ni) {
        const int n_local = wn * 64 + ni * 16 + (l & 15);
        const int m_base = wm * 64 + mi * 16 + (l >> 4) * 4;
#pragma unroll
        for (int r = 0; r < 4; r += 2) {
          const int m_local = m_base + r;
          const unsigned pk = (unsigned)f2bf(acc[mi][ni][r] + bb[ni]) |
                              ((unsigned)f2bf(acc[mi][ni][r + 1] + bb[ni]) << 16);
          const int byte = n_local * 256 + ((m_local * 2) ^ ((n_local & 15) << 3));
          *reinterpret_cast<unsigned*>(smem + byte) = pk;
        }
      }
    __syncthreads();
    const int nrow0 = w * 32;
    for (int rr = 0; rr < 32; ++rr) {
      const int n_local = nrow0 + rr;
      const int n_in = (ntile - 12) * 128 + n_local;
      const int h = n_in / 96, d = n_in - h * 96;
#pragma unroll
      for (int seg = 0; seg < 2; ++seg) {
        const int m_local = seg * 64 + l;
        const int byte = n_local * 256 + ((m_local * 2) ^ ((n_local & 15) << 3));
        const unsigned short val = *reinterpret_cast<unsigned short*>(smem + byte);
        const int m = mtile * 128 + m_local;
        if (m < kM) {
          const int b = m / 577, col = m - b * 577;
          Vt[((size_t)(b * 8 + h) * 96 + d) * 640 + col] = val;
        }
      }
    }
  } else {
    int hh[4], dd[4];
#pragma unroll
    for (int ni = 0; ni < 4; ++ni) {
      const int n_in = (ntile % 6) * 128 + wn * 64 + ni * 16 + (l & 15);
      hh[ni] = n_in / 96;
      dd[ni] = n_in - hh[ni] * 96;
    }
    unsigned short* dst = (matrix == 0) ? Q : K;
#pragma unroll
    for (int mi = 0; mi < 4; ++mi) {
#pragma unroll
      for (int r = 0; r < 4; ++r) {
        const int m = mtile * 128 + wm * 64 + mi * 16 + (l >> 4) * 4 + r;
        if (m >= kM) continue;
        const int bidx = m / 577;
        const int n = m - bidx * 577;
#pragma unroll
        for (int ni = 0; ni < 4; ++ni) {
          const float val = acc[mi][ni][r] + bb[ni];
          const size_t o = ((size_t)(bidx * 8 + hh[ni]) * 577 + n) * 96 + dd[ni];
          dst[o] = f2bf(val);
        }
      }
    }
  }
}

// ---------------- kernel 3: fused flash attention (8 waves, QBLK=128) ----------------
// (R13-exact known-good body; launch_bounds relaxed (512,4)->(512,2): occupancy
// is LDS-bound at 2 blocks/CU either way, this only lifts the 128-VGPR cap.)
__global__ __launch_bounds__(512, 2) void k_attn(
    const unsigned short* __restrict__ Q, const unsigned short* __restrict__ K,
    const unsigned short* __restrict__ Vt, float* __restrict__ out) {
  extern __shared__ char asmem[];  // buf0@0, buf1@28672 (K 16K, V@+16384 12K), sP@57344
  // XCD swizzle: 2560 blocks = 8 x 320; same-bh blocks land on one XCD
  int wk = blockIdx.x;
  {
    const int xcd = wk & 7, i = wk >> 3;
    wk = xcd * 320 + i;
  }
  const int bh = wk / 5, qt = wk - bh * 5;
  const int tid = threadIdx.x, w = tid >> 6, l = tid & 63;
  const int bb_ = bh >> 3, hh_ = bh & 7;
  const size_t hdbase = (size_t)bh * 577 * 96;
  char* const pS = asmem + 57344 + w * 2304;  // per-wave P: [16 q][72 bf16]

  const int qrow = qt * 128 + w * 16 + (l & 15);
  const int qn = (qrow > 576) ? 576 : qrow;

  bf16x8 fq[3];
#pragma unroll
  for (int ks = 0; ks < 3; ++ks) {
    const size_t off = hdbase + (size_t)qn * 96 + ks * 32 + (l >> 4) * 8;
    fq[ks] = *reinterpret_cast<const bf16x8*>(Q + off);
  }

  auto stage = [&](int kt, char* buf) {
    if (w < 7) {
#pragma unroll
      for (int i2 = 0; i2 < 4; ++i2) {
        const int j = w * 4 + i2;  // 0..27
        if (j < 16) {
          const int r = 4 * j + (l >> 4);
          const int lc = (l & 15) ^ (r & 7);
          const int lc2 = (lc < 12) ? lc : 11;
          int kvn = kt * 64 + r; if (kvn > 576) kvn = 576;
          gload16(K + hdbase + (size_t)kvn * 96 + lc2 * 8, buf + j * 1024);
        } else {
          const int u = j - 16;
          const int d = 8 * u + (l >> 3);
          const int lc = (l & 7) ^ (d & 7);
          gload16(Vt + (size_t)(bh * 96 + d) * 640 + kt * 64 + lc * 8,
                  buf + 16384 + u * 1024);
        }
      }
    }
  };

  f32x4 accO[6];
  const f32x4 fz = {0.f, 0.f, 0.f, 0.f};
#pragma unroll
  for (int i = 0; i < 6; ++i) accO[i] = fz;
  float lrun = 0.f;

  stage(0, asmem);

  for (int kt = 0; kt < 10; ++kt) {
    char* cur = asmem + (kt & 1) * 28672;
    if (kt < 9) {
      stage(kt + 1, asmem + ((kt + 1) & 1) * 28672);
      asm volatile("s_waitcnt vmcnt(4)" ::: "memory");
    } else {
      asm volatile("s_waitcnt vmcnt(0)" ::: "memory");
    }
    __builtin_amdgcn_s_barrier();
    __builtin_amdgcn_sched_barrier(0);

    // ---- S^T = K · Q^T ----
    f32x4 s_[4];
#pragma unroll
    for (int i = 0; i < 4; ++i) s_[i] = fz;
#pragma unroll
    for (int ks = 0; ks < 3; ++ks) {
#pragma unroll
      for (int af = 0; af < 4; ++af) {
        const int r = af * 16 + (l & 15);
        const int c16 = ((ks * 4) + (l >> 4)) ^ (r & 7);
        const bf16x8 kf = *reinterpret_cast<const bf16x8*>(cur + r * 256 + c16 * 16);
        s_[af] = MFMA16(kf, fq[ks], s_[af]);
      }
    }

    if (kt == 9) {  // mask kv >= 577
#pragma unroll
      for (int af = 0; af < 4; ++af) {
        const int kv0 = 576 + af * 16 + (l >> 4) * 4;
#pragma unroll
        for (int r = 0; r < 4; ++r)
          if (kv0 + r >= 577) s_[af][r] = -1e30f;
      }
    }

    // ---- P = exp(S); per-lane running sum; pack via v_cvt_pk_bf16_f32 ----
    float psum = 0.f;
    char* pbase = pS + (l & 15) * 144;
#pragma unroll
    for (int af = 0; af < 4; ++af) {
      const float p0 = __expf(s_[af][0]);
      const float p1 = __expf(s_[af][1]);
      const float p2 = __expf(s_[af][2]);
      const float p3 = __expf(s_[af][3]);
      psum += (p0 + p1) + (p2 + p3);
      unsigned w0, w1;
      asm("v_cvt_pk_bf16_f32 %0, %1, %2" : "=v"(w0) : "v"(p0), "v"(p1));
      asm("v_cvt_pk_bf16_f32 %0, %1, %2" : "=v"(w1) : "v"(p2), "v"(p3));
      uint2 ww; ww.x = w0; ww.y = w1;
      *reinterpret_cast<uint2*>(pbase + af * 32 + (l >> 4) * 8) = ww;
    }
    lrun += psum;
    // P is per-wave: lgkm drain orders ds_write -> ds_read within the wave
    asm volatile("s_waitcnt lgkmcnt(0)" ::: "memory");
    __builtin_amdgcn_sched_barrier(0);

    // ---- O^T += V^T · P^T ----
#pragma unroll
    for (int ks = 0; ks < 2; ++ks) {
      const bf16x8 pb = *reinterpret_cast<const bf16x8*>(
          pS + (l & 15) * 144 + ks * 64 + (l >> 4) * 16);
#pragma unroll
      for (int df = 0; df < 6; ++df) {
        const int r = df * 16 + (l & 15);
        const int c16 = ((ks * 4) + (l >> 4)) ^ (r & 7);
        const bf16x8 va = *reinterpret_cast<const bf16x8*>(
            cur + 16384 + r * 128 + c16 * 16);
        accO[df] = MFMA16(va, pb, accO[df]);
      }
    }
    // end barrier: all waves' reads of cur done before kt+1 stages overwrite it
    asm volatile("s_waitcnt lgkmcnt(0)" ::: "memory");
    __builtin_amdgcn_s_barrier();
    __builtin_amdgcn_sched_barrier(0);
  }

  // ---- epilogue: reduce l across the 4 lane-groups; out = O * scale / l ----
  lrun += __shfl_xor(lrun, 16, 64);
  lrun += __shfl_xor(lrun, 32, 64);
  if (qrow <= 576) {
    const float inv = kScale / lrun;
#pragma unroll
    for (int df = 0; df < 6; ++df) {
      float4 o;
      o.x = accO[df][0] * inv; o.y = accO[df][1] * inv;
      o.z = accO[df][2] * inv; o.w = accO[df][3] * inv;
      const size_t oo = ((size_t)bb_ * 577 + qrow) * 768 + hh_ * 96 + df * 16 + (l >> 4) * 4;
      *reinterpret_cast<float4*>(out + oo) = o;
    }
  }
}

extern "C" void kernel_launch(void* const* d_in, const int* in_sizes, int n_in,
                              void* d_out, int out_size, void* d_ws, size_t ws_size,
                              hipStream_t stream) {
  const float* x  = (const float*)d_in[0];
  const float* Wq = (const float*)d_in[1];
  const float* bq = (const float*)d_in[2];
  const float* Wk = (const float*)d_in[3];
  const float* bk = (const float*)d_in[4];
  const float* Wv = (const float*)d_in[5];
  const float* bv = (const float*)d_in[6];
  float* out = (float*)d_out;
  char* ws = (char*)d_ws;

  const size_t SZ = 56721408;  // 36928*768*2 bytes
  unsigned short* xh   = (unsigned short*)(ws);
  unsigned short* wcat = (unsigned short*)(ws + SZ);                    // 3538944 B
  unsigned short* Q    = (unsigned short*)(ws + SZ + 3538944);
  unsigned short* K    = (unsigned short*)(ws + 2 * SZ + 3538944);
  unsigned short* Vt   = (unsigned short*)(ws + 3 * SZ + 3538944);      // 62914560 B

  hipFuncSetAttribute((const void*)k_proj,
                      hipFuncAttributeMaxDynamicSharedMemorySize, 65536);
  hipFuncSetAttribute((const void*)k_attn,
                      hipFuncAttributeMaxDynamicSharedMemorySize, 75776);

  k_prep<<<29424, 256, 0, stream>>>(x, Wq, Wk, Wv, xh, wcat);
  k_proj<<<dim3(5202), 256, 65536, stream>>>(xh, wcat, bq, bk, bv, Q, K, Vt);
  k_attn<<<dim3(2560), 512, 75776, stream>>>(Q, K, Vt, out);
}